// Round 5
// baseline (541.995 us; speedup 1.0000x reference)
//
#include <hip/hip_runtime.h>

// QECC statevector: 23 qubits, DIM = 2^23 amplitudes, N0 = 2 vectors per code.
// Gate ind0 acts on statevector bit p = 22 - ind0:  new_d = sum_b old_b * U[b,d].
// Split: k_low does statevector bits 0..12 (gates q=22..10), k_high bits 13..22
// (gates q=9..0) + fused overlap dot. Intermediate ws is TRANSPOSED with a
// 4-element e-granule (R7 layout):
//   W(i, g2, h, e) = i*DIM + g2*4096 + h*4 + e     (h = idx>>13, l = idx&8191,
//                                                   g2 = l>>2, e = l&3)
// so k_high block g2 reads one contiguous 32 KB chunk per (block,i).
//
// R7: R6 closed the traffic story (FETCH = 132 MB = ws only; c1 fully
// cache-served) but k_high's dur didn't move (151->153 us) -> never BW-bound.
// OccupancyPercent ~21% across ALL rounds ~= 8 waves = ONE 512-thr/64KB block
// per CU: all load/barrier/dot stalls fully exposed, no sibling to cover them.
// Fix: k_high goes to 256 threads / 32 KB LDS / 4096-elem chunks / 2048 blocks
// (same 16-reg 3-phase structure, same fused dot -> same no-spill codegen),
// targeting 2-4 co-resident blocks per CU. k_low only changes its ws write
// addressing (e-granule 8->4; 32B half-lines pair across H^1 -> same-XCD L2
// merge via the existing pair swizzle, the mechanism R6 proved for c1).
//
// NOTE on __launch_bounds__: measured R2 showed hipcc treats the 2nd arg as
// CUDA-style min BLOCKS per CU: (512,4) -> 32 waves/CU -> 64-VGPR cap -> 401 MB
// of spill traffic. (512,2)/(256,4) -> cap 128.
#define DIM_ (1 << 23)
#define N0_ 2

typedef float f32x4 __attribute__((ext_vector_type(4)));

// overlap accumulators {R00,I00,R01,I01,R10,I10,R11,I11}; zeroed each launch
__device__ float g_acc[8];

// LDS bank swizzle (bits 0,1 ^= bits 5,6 ; bits 2..4 ^= bits 7..9), bijective.
__device__ __forceinline__ int swz(int x) {
    return x ^ ((x >> 5) & 3) ^ (((x >> 7) & 7) << 2);
}

// XCD swizzle: round-robin dispatch puts linear block b on XCD b%8; map b so
// each XCD owns a CONTIGUOUS chunk range -> chunks sharing 64B lines land on
// the same XCD's L2. Bijective for grid = 8*CPX.
template <int CPX>
__device__ __forceinline__ int xcd_swz(int b) {
    return (b & 7) * CPX + (b >> 3);
}

__device__ __forceinline__ void gload(const float* __restrict__ ur,
                                      const float* __restrict__ ui, int q,
                                      float2& u00, float2& u01, float2& u10, float2& u11) {
    u00 = make_float2(ur[q * 4 + 0], ui[q * 4 + 0]);
    u01 = make_float2(ur[q * 4 + 1], ui[q * 4 + 1]);
    u10 = make_float2(ur[q * 4 + 2], ui[q * 4 + 2]);
    u11 = make_float2(ur[q * 4 + 3], ui[q * 4 + 3]);
}

// out0 = u00*a0 + u10*a1 ; out1 = u01*a0 + u11*a1   (complex, einsum convention)
__device__ __forceinline__ void bfly(float2& a0, float2& a1,
                                     float2 u00, float2 u01, float2 u10, float2 u11) {
    float2 n0, n1;
    n0.x = a0.x * u00.x - a0.y * u00.y + a1.x * u10.x - a1.y * u10.y;
    n0.y = a0.x * u00.y + a0.y * u00.x + a1.x * u10.y + a1.y * u10.x;
    n1.x = a0.x * u01.x - a0.y * u01.y + a1.x * u11.x - a1.y * u11.y;
    n1.y = a0.x * u01.y + a0.y * u01.x + a1.x * u11.y + a1.y * u11.x;
    a0 = n0; a1 = n1;
}

// Butterfly all pairs of the 16-register file v[] differing in bit log2(S), gate Q.
#define BFLY16(S, Q)                                                           \
    do {                                                                       \
        float2 u00, u01, u10, u11;                                             \
        gload(ur, ui, (Q), u00, u01, u10, u11);                                \
        _Pragma("unroll")                                                      \
        for (int m0 = 0; m0 < 16; ++m0)                                        \
            if (!(m0 & (S))) bfly(v[m0], v[m0 + (S)], u00, u01, u10, u11);     \
    } while (0)

// ---------------------------------------------------------------------------
// K1: low 13 bits. Block (H, i) owns the contiguous chunk idx = H*8192 + l.
// 512 thr x 16 complex regs. Phases (4 bits each in regs, LDS remaps between):
//   A: l bits {0,1,11,12} -> q22,q21,q11,q10      (from float4 load layout)
//   B: l bits {2..5}      -> q20..q17
//   C: l bits {6..9}      -> q16..q13
//   readout: pairs (x, x^1024) -> q12, then store transposed (or identity for
//   the in-place fallback).
// ---------------------------------------------------------------------------
template <bool INTER>
__global__ __launch_bounds__(512, 2) void k_low(
    const float* __restrict__ inr, const float* __restrict__ ini,
    const float* __restrict__ ur, const float* __restrict__ ui,
    float2* __restrict__ outI, float* __restrict__ outR, float* __restrict__ outJ) {
    __shared__ float2 buf[8192];  // 64 KB
    const int t = threadIdx.x;
    const int H = xcd_swz<128>(blockIdx.x);   // high-10-bit value this block owns
    const int base = blockIdx.y * DIM_ + (H << 13);

    float2 v[16];
    // load: reg m = (k<<2)|j  <->  l = (k<<11)|(t<<2)|j   (nt: c0 is read-once)
#pragma unroll
    for (int k = 0; k < 4; ++k) {
        const int y = (k << 11) | (t << 2);
        const f32x4 re = __builtin_nontemporal_load((const f32x4*)(inr + base + y));
        const f32x4 im = __builtin_nontemporal_load((const f32x4*)(ini + base + y));
        v[k * 4 + 0] = make_float2(re.x, im.x);
        v[k * 4 + 1] = make_float2(re.y, im.y);
        v[k * 4 + 2] = make_float2(re.z, im.z);
        v[k * 4 + 3] = make_float2(re.w, im.w);
    }
    // Phase A: m0=l0->q22, m1=l1->q21, m2=l11->q11, m3=l12->q10
    BFLY16(1, 22);
    BFLY16(2, 21);
    BFLY16(4, 11);
    BFLY16(8, 10);
#pragma unroll
    for (int m = 0; m < 16; ++m)
        buf[swz(((m >> 2) << 11) | (t << 2) | (m & 3))] = v[m];
    __syncthreads();
    // Phase B: m = l bits 2..5 ; x = (t&3) | (m<<2) | ((t>>2)<<6)
#pragma unroll
    for (int m = 0; m < 16; ++m)
        v[m] = buf[swz((t & 3) | (m << 2) | ((t >> 2) << 6))];
    BFLY16(1, 20);
    BFLY16(2, 19);
    BFLY16(4, 18);
    BFLY16(8, 17);
#pragma unroll
    for (int m = 0; m < 16; ++m)
        buf[swz((t & 3) | (m << 2) | ((t >> 2) << 6))] = v[m];  // same slots: no race
    __syncthreads();
    // Phase C: m = l bits 6..9 ; x = (t&63) | (m<<6) | ((t>>6)<<10)
#pragma unroll
    for (int m = 0; m < 16; ++m)
        v[m] = buf[swz((t & 63) | (m << 6) | ((t >> 6) << 10))];
    BFLY16(1, 16);
    BFLY16(2, 15);
    BFLY16(4, 14);
    BFLY16(8, 13);
#pragma unroll
    for (int m = 0; m < 16; ++m)
        buf[swz((t & 63) | (m << 6) | ((t >> 6) << 10))] = v[m];
    __syncthreads();
    // Readout + q12 (l bit 10 = pairs x, x^1024), stores 2 complex per float4.
    {
        float2 u00, u01, u10, u11;
        gload(ur, ui, 12, u00, u01, u10, u11);
#pragma unroll
        for (int rp = 0; rp < 4; ++rp) {
            const int x0 = (rp << 11) | (t << 1);  // even, bit10 = 0
            float2 a0 = buf[swz(x0)];
            float2 a1 = buf[swz(x0 | 1)];
            float2 b0 = buf[swz(x0 | 1024)];
            float2 b1 = buf[swz(x0 | 1025)];
            bfly(a0, b0, u00, u01, u10, u11);
            bfly(a1, b1, u00, u01, u10, u11);
            if (INTER) {
                // R7 transposed layout: o = (l>>2)*4096 + H*4 + (l&3).
                // (a0,a1) are l, l|1 -> same g2, adjacent e -> one float4.
                const int l0 = x0, l1 = x0 | 1024;
                const int o0 = ((l0 >> 2) << 12) | (H << 2) | (l0 & 3);
                const int o1 = ((l1 >> 2) << 12) | (H << 2) | (l1 & 3);
                float2* p = outI + blockIdx.y * DIM_;
                *(float4*)(p + o0) = make_float4(a0.x, a0.y, a1.x, a1.y);
                *(float4*)(p + o1) = make_float4(b0.x, b0.y, b1.x, b1.y);
            } else {
                // identity layout, in-place safe (block writes only its own chunk)
                *(float2*)(outR + base + x0) = make_float2(a0.x, a1.x);
                *(float2*)(outJ + base + x0) = make_float2(a0.y, a1.y);
                *(float2*)(outR + base + (x0 | 1024)) = make_float2(b0.x, b1.x);
                *(float2*)(outJ + base + (x0 | 1024)) = make_float2(b0.y, b1.y);
            }
        }
    }
}

// ---------------------------------------------------------------------------
// One 10-bit high-pass for vector i (R7: 256 threads, 4096-elem chunk, 32 KB).
// Chunk = l-group g2 (l = g2*4 + e, e<4), spanning h=0..1023. Register m of
// thread t holds y = ((m>>2)<<10)|(t<<2)|(m&3) where h = y>>2, e = y&3.
// Phases: A: m bits 2,3 = h bits 8,9 -> gates q1,q0
//         B: m = h bits 0..3 -> gates q9..q6
//         C: m = h bits 4..7 -> gates q5..q2
// Exit layout: y = (t&63) | (m<<6) | ((t>>6)<<10). No trailing __syncthreads.
// ---------------------------------------------------------------------------
template <bool INTER>
__device__ __forceinline__ void high_pass(
    float2 (&v)[16], float2* buf, const int t, const int g2, const int i,
    const float2* __restrict__ wsI, const float* __restrict__ wsR,
    const float* __restrict__ wsJ,
    const float* __restrict__ ur, const float* __restrict__ ui) {
    if constexpr (INTER) {
        // contiguous 32 KB chunk; nontemporal: ws is read exactly once
        const f32x4* wsv = (const f32x4*)(wsI + i * DIM_ + (g2 << 12));
#pragma unroll
        for (int k = 0; k < 4; ++k)
#pragma unroll
            for (int jh = 0; jh < 2; ++jh) {
                const f32x4 f =
                    __builtin_nontemporal_load(wsv + ((k << 9) | (t << 1) | jh));
                v[k * 4 + jh * 2 + 0] = make_float2(f.x, f.y);
                v[k * 4 + jh * 2 + 1] = make_float2(f.z, f.w);
            }
    } else {
        // identity-layout fallback: idx = h*8192 + g2*4 + e
#pragma unroll
        for (int k = 0; k < 4; ++k) {
            const int y0 = (k << 10) | (t << 2);
            const int a = ((y0 >> 2) << 13) | (g2 << 2);
            const f32x4 re = *(const f32x4*)(wsR + i * DIM_ + a);
            const f32x4 im = *(const f32x4*)(wsJ + i * DIM_ + a);
            v[k * 4 + 0] = make_float2(re.x, im.x);
            v[k * 4 + 1] = make_float2(re.y, im.y);
            v[k * 4 + 2] = make_float2(re.z, im.z);
            v[k * 4 + 3] = make_float2(re.w, im.w);
        }
    }
    // Phase A: reg m2,m3 = y bits 10,11 = h bits 8,9 -> gates q1,q0
    BFLY16(4, 1);
    BFLY16(8, 0);
#pragma unroll
    for (int m = 0; m < 16; ++m)
        buf[swz(((m >> 2) << 10) | (t << 2) | (m & 3))] = v[m];
    __syncthreads();
    // Phase B: m = h bits 0..3 = y bits 2..5 ; x = (t&3) | (m<<2) | ((t>>2)<<6)
#pragma unroll
    for (int m = 0; m < 16; ++m)
        v[m] = buf[swz((t & 3) | (m << 2) | ((t >> 2) << 6))];
    BFLY16(1, 9);
    BFLY16(2, 8);
    BFLY16(4, 7);
    BFLY16(8, 6);
#pragma unroll
    for (int m = 0; m < 16; ++m)
        buf[swz((t & 3) | (m << 2) | ((t >> 2) << 6))] = v[m];  // same slots
    __syncthreads();
    // Phase C: m = h bits 4..7 = y bits 6..9 ; x = (t&63) | (m<<6) | ((t>>6)<<10)
#pragma unroll
    for (int m = 0; m < 16; ++m)
        v[m] = buf[swz((t & 63) | (m << 6) | ((t >> 6) << 10))];
    BFLY16(1, 5);
    BFLY16(2, 4);
    BFLY16(4, 3);
    BFLY16(8, 2);
}

// ---------------------------------------------------------------------------
// K2 (R7): 256 thr, 32 KB LDS, 2048 blocks; block owns l-group g2 (l=g2*4+e).
// Transforms i=0 into v0, i=1 into v1 (both in registers), then a SINGLE
// fused dot reading c1 once. Keeping v0+v1 live through the dot is what
// forces the allocator to throttle c1 load batching -- measured R2/R6:
// VGPR=108, zero spill (split-dot variants R3-R5: VGPR=128 + ~100 MB spills).
// XCD swizzle: 64B c1 line = 4 consecutive g2 chunks; swz groups 256
// consecutive g2 per XCD -> line-mates share an L2.
// ---------------------------------------------------------------------------
template <bool INTER>
__global__ __launch_bounds__(256, 4) void k_high(
    const float2* __restrict__ wsI, const float* __restrict__ wsR, const float* __restrict__ wsJ,
    const float* __restrict__ c1r, const float* __restrict__ c1i,
    const float* __restrict__ ur, const float* __restrict__ ui) {
    __shared__ float2 buf[4096];  // 32 KB; reused as reduction scratch
    const int t = threadIdx.x;
    const int g2 = xcd_swz<256>(blockIdx.x);  // l-group, 2048 blocks
    float acc[8];
#pragma unroll
    for (int k = 0; k < 8; ++k) acc[k] = 0.f;

    float2 v0[16], v1[16];
    high_pass<INTER>(v0, buf, t, g2, 0, wsI, wsR, wsJ, ur, ui);
    __syncthreads();  // buf handoff between passes
    high_pass<INTER>(v1, buf, t, g2, 1, wsI, wsR, wsJ, ur, ui);

    // Fused dot: overlap_ij += conj(c0'_i) * c1_j ; c1 read ONCE.
#pragma unroll
    for (int m = 0; m < 16; ++m) {
        const int y = (t & 63) | (m << 6) | ((t >> 6) << 10);
        const int idx = ((y >> 2) << 13) | (g2 << 2) | (y & 3);
        const float ar = c1r[idx], ai = c1i[idx];
        const float br = c1r[DIM_ + idx], bi = c1i[DIM_ + idx];
        acc[0] += v0[m].x * ar + v0[m].y * ai;
        acc[1] += v0[m].x * ai - v0[m].y * ar;
        acc[2] += v0[m].x * br + v0[m].y * bi;
        acc[3] += v0[m].x * bi - v0[m].y * br;
        acc[4] += v1[m].x * ar + v1[m].y * ai;
        acc[5] += v1[m].x * ai - v1[m].y * ar;
        acc[6] += v1[m].x * br + v1[m].y * bi;
        acc[7] += v1[m].x * bi - v1[m].y * br;
    }

    // wave (64) shuffle reduce -> cross-wave LDS -> one atomic per block
#pragma unroll
    for (int k = 0; k < 8; ++k)
#pragma unroll
        for (int off = 32; off > 0; off >>= 1)
            acc[k] += __shfl_down(acc[k], off, 64);
    __syncthreads();  // all waves past their buf reads before reuse as scratch
    float* red = (float*)buf;
    const int wave = t >> 6, lane = t & 63;
    if (lane == 0) {
#pragma unroll
        for (int k = 0; k < 8; ++k) red[wave * 8 + k] = acc[k];
    }
    __syncthreads();
    if (t < 8) {
        float s = 0.f;
#pragma unroll
        for (int w = 0; w < 4; ++w) s += red[w * 8 + t];
        atomicAdd(&g_acc[t], s);
    }
}

__global__ void k_zero() {
    if (threadIdx.x < 8) g_acc[threadIdx.x] = 0.f;
}

__global__ void k_fin(float* __restrict__ out) {
    if (threadIdx.x == 0) {
        float s = 0.f;
#pragma unroll
        for (int k = 0; k < 4; ++k)
            s += g_acc[2 * k] * g_acc[2 * k] + g_acc[2 * k + 1] * g_acc[2 * k + 1];
        out[0] = (float)N0_ - s;
    }
}

extern "C" void kernel_launch(void* const* d_in, const int* in_sizes, int n_in,
                              void* d_out, int out_size, void* d_ws, size_t ws_size,
                              hipStream_t stream) {
    const float* c0r = (const float*)d_in[0];
    const float* c0i = (const float*)d_in[1];
    const float* c1r = (const float*)d_in[2];
    const float* c1i = (const float*)d_in[3];
    const float* ur  = (const float*)d_in[4];
    const float* ui  = (const float*)d_in[5];
    float* out = (float*)d_out;

    const size_t need = (size_t)N0_ * DIM_ * sizeof(float2);  // 128 MB intermediate
    k_zero<<<1, 64, 0, stream>>>();
    dim3 g1(1024, N0_);
    if (d_ws != nullptr && ws_size >= need) {
        float2* wsI = (float2*)d_ws;
        k_low<true><<<g1, 512, 0, stream>>>(c0r, c0i, ur, ui, wsI, nullptr, nullptr);
        k_high<true><<<2048, 256, 0, stream>>>(wsI, nullptr, nullptr, c1r, c1i, ur, ui);
    } else {
        // fallback: identity layout, in place into code0 planes (harness restores
        // d_in from pristine copies before every timed launch)
        float* oR = (float*)c0r;
        float* oJ = (float*)c0i;
        k_low<false><<<g1, 512, 0, stream>>>(c0r, c0i, ur, ui, nullptr, oR, oJ);
        k_high<false><<<2048, 256, 0, stream>>>(nullptr, oR, oJ, c1r, c1i, ur, ui);
    }
    k_fin<<<1, 64, 0, stream>>>(out);
}

// Round 6
// 391.649 us; speedup vs baseline: 1.3839x; 1.3839x over previous
//
#include <hip/hip_runtime.h>

// QECC statevector: 23 qubits, DIM = 2^23 amplitudes, N0 = 2 vectors per code.
// Gate ind0 acts on statevector bit p = 22 - ind0:  new_d = sum_b old_b * U[b,d].
// Split: k_low does statevector bits 0..12 (gates q=22..10), k_high bits 13..22
// (gates q=9..0) + fused overlap dot. Intermediate ws is TRANSPOSED with a
// 4-element e-granule:
//   W(i, g2, h, e) = i*DIM + g2*4096 + h*4 + e     (h = idx>>13, l = idx&8191,
//                                                   g2 = l>>2, e = l&3)
// so k_high block g2 reads one contiguous 32 KB chunk per (block,i).
//
// R8: R7's 256-thr restructure was sound but __launch_bounds__(256,4) imposed
// a 64-VGPR cap (measured VGPR=64, 476 MB scratch spills, 321 us). Empirical
// cap table on this toolchain: (512,4)->64, (512,2)->128, (256,4)->64.
// Only change this round: (256,2) -> cap >=128, compiler should return to the
// proven ~108-VGPR no-spill codegen; at 108<=128 VGPR hardware occupancy steps
// to 4 waves/SIMD = 16 waves/CU = 4 blocks/CU (LDS 4x32KB=128<=160KB), double
// R6's single-block residency, with independent blocks anti-phasing stalls.
#define DIM_ (1 << 23)
#define N0_ 2

typedef float f32x4 __attribute__((ext_vector_type(4)));

// overlap accumulators {R00,I00,R01,I01,R10,I10,R11,I11}; zeroed each launch
__device__ float g_acc[8];

// LDS bank swizzle (bits 0,1 ^= bits 5,6 ; bits 2..4 ^= bits 7..9), bijective.
__device__ __forceinline__ int swz(int x) {
    return x ^ ((x >> 5) & 3) ^ (((x >> 7) & 7) << 2);
}

// XCD swizzle: round-robin dispatch puts linear block b on XCD b%8; map b so
// each XCD owns a CONTIGUOUS chunk range -> chunks sharing 64B lines land on
// the same XCD's L2. Bijective for grid = 8*CPX.
template <int CPX>
__device__ __forceinline__ int xcd_swz(int b) {
    return (b & 7) * CPX + (b >> 3);
}

__device__ __forceinline__ void gload(const float* __restrict__ ur,
                                      const float* __restrict__ ui, int q,
                                      float2& u00, float2& u01, float2& u10, float2& u11) {
    u00 = make_float2(ur[q * 4 + 0], ui[q * 4 + 0]);
    u01 = make_float2(ur[q * 4 + 1], ui[q * 4 + 1]);
    u10 = make_float2(ur[q * 4 + 2], ui[q * 4 + 2]);
    u11 = make_float2(ur[q * 4 + 3], ui[q * 4 + 3]);
}

// out0 = u00*a0 + u10*a1 ; out1 = u01*a0 + u11*a1   (complex, einsum convention)
__device__ __forceinline__ void bfly(float2& a0, float2& a1,
                                     float2 u00, float2 u01, float2 u10, float2 u11) {
    float2 n0, n1;
    n0.x = a0.x * u00.x - a0.y * u00.y + a1.x * u10.x - a1.y * u10.y;
    n0.y = a0.x * u00.y + a0.y * u00.x + a1.x * u10.y + a1.y * u10.x;
    n1.x = a0.x * u01.x - a0.y * u01.y + a1.x * u11.x - a1.y * u11.y;
    n1.y = a0.x * u01.y + a0.y * u01.x + a1.x * u11.y + a1.y * u11.x;
    a0 = n0; a1 = n1;
}

// Butterfly all pairs of the 16-register file v[] differing in bit log2(S), gate Q.
#define BFLY16(S, Q)                                                           \
    do {                                                                       \
        float2 u00, u01, u10, u11;                                             \
        gload(ur, ui, (Q), u00, u01, u10, u11);                                \
        _Pragma("unroll")                                                      \
        for (int m0 = 0; m0 < 16; ++m0)                                        \
            if (!(m0 & (S))) bfly(v[m0], v[m0 + (S)], u00, u01, u10, u11);     \
    } while (0)

// ---------------------------------------------------------------------------
// K1: low 13 bits. Block (H, i) owns the contiguous chunk idx = H*8192 + l.
// 512 thr x 16 complex regs. Phases (4 bits each in regs, LDS remaps between):
//   A: l bits {0,1,11,12} -> q22,q21,q11,q10      (from float4 load layout)
//   B: l bits {2..5}      -> q20..q17
//   C: l bits {6..9}      -> q16..q13
//   readout: pairs (x, x^1024) -> q12, then store transposed (or identity for
//   the in-place fallback).
// ---------------------------------------------------------------------------
template <bool INTER>
__global__ __launch_bounds__(512, 2) void k_low(
    const float* __restrict__ inr, const float* __restrict__ ini,
    const float* __restrict__ ur, const float* __restrict__ ui,
    float2* __restrict__ outI, float* __restrict__ outR, float* __restrict__ outJ) {
    __shared__ float2 buf[8192];  // 64 KB
    const int t = threadIdx.x;
    const int H = xcd_swz<128>(blockIdx.x);   // high-10-bit value this block owns
    const int base = blockIdx.y * DIM_ + (H << 13);

    float2 v[16];
    // load: reg m = (k<<2)|j  <->  l = (k<<11)|(t<<2)|j   (nt: c0 is read-once)
#pragma unroll
    for (int k = 0; k < 4; ++k) {
        const int y = (k << 11) | (t << 2);
        const f32x4 re = __builtin_nontemporal_load((const f32x4*)(inr + base + y));
        const f32x4 im = __builtin_nontemporal_load((const f32x4*)(ini + base + y));
        v[k * 4 + 0] = make_float2(re.x, im.x);
        v[k * 4 + 1] = make_float2(re.y, im.y);
        v[k * 4 + 2] = make_float2(re.z, im.z);
        v[k * 4 + 3] = make_float2(re.w, im.w);
    }
    // Phase A: m0=l0->q22, m1=l1->q21, m2=l11->q11, m3=l12->q10
    BFLY16(1, 22);
    BFLY16(2, 21);
    BFLY16(4, 11);
    BFLY16(8, 10);
#pragma unroll
    for (int m = 0; m < 16; ++m)
        buf[swz(((m >> 2) << 11) | (t << 2) | (m & 3))] = v[m];
    __syncthreads();
    // Phase B: m = l bits 2..5 ; x = (t&3) | (m<<2) | ((t>>2)<<6)
#pragma unroll
    for (int m = 0; m < 16; ++m)
        v[m] = buf[swz((t & 3) | (m << 2) | ((t >> 2) << 6))];
    BFLY16(1, 20);
    BFLY16(2, 19);
    BFLY16(4, 18);
    BFLY16(8, 17);
#pragma unroll
    for (int m = 0; m < 16; ++m)
        buf[swz((t & 3) | (m << 2) | ((t >> 2) << 6))] = v[m];  // same slots: no race
    __syncthreads();
    // Phase C: m = l bits 6..9 ; x = (t&63) | (m<<6) | ((t>>6)<<10)
#pragma unroll
    for (int m = 0; m < 16; ++m)
        v[m] = buf[swz((t & 63) | (m << 6) | ((t >> 6) << 10))];
    BFLY16(1, 16);
    BFLY16(2, 15);
    BFLY16(4, 14);
    BFLY16(8, 13);
#pragma unroll
    for (int m = 0; m < 16; ++m)
        buf[swz((t & 63) | (m << 6) | ((t >> 6) << 10))] = v[m];
    __syncthreads();
    // Readout + q12 (l bit 10 = pairs x, x^1024), stores 2 complex per float4.
    {
        float2 u00, u01, u10, u11;
        gload(ur, ui, 12, u00, u01, u10, u11);
#pragma unroll
        for (int rp = 0; rp < 4; ++rp) {
            const int x0 = (rp << 11) | (t << 1);  // even, bit10 = 0
            float2 a0 = buf[swz(x0)];
            float2 a1 = buf[swz(x0 | 1)];
            float2 b0 = buf[swz(x0 | 1024)];
            float2 b1 = buf[swz(x0 | 1025)];
            bfly(a0, b0, u00, u01, u10, u11);
            bfly(a1, b1, u00, u01, u10, u11);
            if (INTER) {
                // transposed layout: o = (l>>2)*4096 + H*4 + (l&3).
                // (a0,a1) are l, l|1 -> same g2, adjacent e -> one float4.
                const int l0 = x0, l1 = x0 | 1024;
                const int o0 = ((l0 >> 2) << 12) | (H << 2) | (l0 & 3);
                const int o1 = ((l1 >> 2) << 12) | (H << 2) | (l1 & 3);
                float2* p = outI + blockIdx.y * DIM_;
                *(float4*)(p + o0) = make_float4(a0.x, a0.y, a1.x, a1.y);
                *(float4*)(p + o1) = make_float4(b0.x, b0.y, b1.x, b1.y);
            } else {
                // identity layout, in-place safe (block writes only its own chunk)
                *(float2*)(outR + base + x0) = make_float2(a0.x, a1.x);
                *(float2*)(outJ + base + x0) = make_float2(a0.y, a1.y);
                *(float2*)(outR + base + (x0 | 1024)) = make_float2(b0.x, b1.x);
                *(float2*)(outJ + base + (x0 | 1024)) = make_float2(b0.y, b1.y);
            }
        }
    }
}

// ---------------------------------------------------------------------------
// One 10-bit high-pass for vector i (256 threads, 4096-elem chunk, 32 KB).
// Chunk = l-group g2 (l = g2*4 + e, e<4), spanning h=0..1023. Register m of
// thread t holds y = ((m>>2)<<10)|(t<<2)|(m&3) where h = y>>2, e = y&3.
// Phases: A: m bits 2,3 = h bits 8,9 -> gates q1,q0
//         B: m = h bits 0..3 -> gates q9..q6
//         C: m = h bits 4..7 -> gates q5..q2
// Exit layout: y = (t&63) | (m<<6) | ((t>>6)<<10). No trailing __syncthreads.
// ---------------------------------------------------------------------------
template <bool INTER>
__device__ __forceinline__ void high_pass(
    float2 (&v)[16], float2* buf, const int t, const int g2, const int i,
    const float2* __restrict__ wsI, const float* __restrict__ wsR,
    const float* __restrict__ wsJ,
    const float* __restrict__ ur, const float* __restrict__ ui) {
    if constexpr (INTER) {
        // contiguous 32 KB chunk; nontemporal: ws is read exactly once
        const f32x4* wsv = (const f32x4*)(wsI + i * DIM_ + (g2 << 12));
#pragma unroll
        for (int k = 0; k < 4; ++k)
#pragma unroll
            for (int jh = 0; jh < 2; ++jh) {
                const f32x4 f =
                    __builtin_nontemporal_load(wsv + ((k << 9) | (t << 1) | jh));
                v[k * 4 + jh * 2 + 0] = make_float2(f.x, f.y);
                v[k * 4 + jh * 2 + 1] = make_float2(f.z, f.w);
            }
    } else {
        // identity-layout fallback: idx = h*8192 + g2*4 + e
#pragma unroll
        for (int k = 0; k < 4; ++k) {
            const int y0 = (k << 10) | (t << 2);
            const int a = ((y0 >> 2) << 13) | (g2 << 2);
            const f32x4 re = *(const f32x4*)(wsR + i * DIM_ + a);
            const f32x4 im = *(const f32x4*)(wsJ + i * DIM_ + a);
            v[k * 4 + 0] = make_float2(re.x, im.x);
            v[k * 4 + 1] = make_float2(re.y, im.y);
            v[k * 4 + 2] = make_float2(re.z, im.z);
            v[k * 4 + 3] = make_float2(re.w, im.w);
        }
    }
    // Phase A: reg m2,m3 = y bits 10,11 = h bits 8,9 -> gates q1,q0
    BFLY16(4, 1);
    BFLY16(8, 0);
#pragma unroll
    for (int m = 0; m < 16; ++m)
        buf[swz(((m >> 2) << 10) | (t << 2) | (m & 3))] = v[m];
    __syncthreads();
    // Phase B: m = h bits 0..3 = y bits 2..5 ; x = (t&3) | (m<<2) | ((t>>2)<<6)
#pragma unroll
    for (int m = 0; m < 16; ++m)
        v[m] = buf[swz((t & 3) | (m << 2) | ((t >> 2) << 6))];
    BFLY16(1, 9);
    BFLY16(2, 8);
    BFLY16(4, 7);
    BFLY16(8, 6);
#pragma unroll
    for (int m = 0; m < 16; ++m)
        buf[swz((t & 3) | (m << 2) | ((t >> 2) << 6))] = v[m];  // same slots
    __syncthreads();
    // Phase C: m = h bits 4..7 = y bits 6..9 ; x = (t&63) | (m<<6) | ((t>>6)<<10)
#pragma unroll
    for (int m = 0; m < 16; ++m)
        v[m] = buf[swz((t & 63) | (m << 6) | ((t >> 6) << 10))];
    BFLY16(1, 5);
    BFLY16(2, 4);
    BFLY16(4, 3);
    BFLY16(8, 2);
}

// ---------------------------------------------------------------------------
// K2: 256 thr, 32 KB LDS, 2048 blocks; block owns l-group g2 (l=g2*4+e).
// Transforms i=0 into v0, i=1 into v1 (both in registers), then a SINGLE
// fused dot reading c1 once. Keeping v0+v1 live through the dot is what
// forces the allocator to throttle c1 load batching -- measured R2/R6:
// VGPR=108, zero spill (split-dot variants R3-R5: VGPR=128 + ~100 MB spills;
// R7's (256,4) bound: VGPR capped 64 -> 476 MB spills).
// XCD swizzle: 64B c1 line = 4 consecutive g2 chunks; swz groups 256
// consecutive g2 per XCD -> line-mates share an L2.
// ---------------------------------------------------------------------------
template <bool INTER>
__global__ __launch_bounds__(256, 2) void k_high(
    const float2* __restrict__ wsI, const float* __restrict__ wsR, const float* __restrict__ wsJ,
    const float* __restrict__ c1r, const float* __restrict__ c1i,
    const float* __restrict__ ur, const float* __restrict__ ui) {
    __shared__ float2 buf[4096];  // 32 KB; reused as reduction scratch
    const int t = threadIdx.x;
    const int g2 = xcd_swz<256>(blockIdx.x);  // l-group, 2048 blocks
    float acc[8];
#pragma unroll
    for (int k = 0; k < 8; ++k) acc[k] = 0.f;

    float2 v0[16], v1[16];
    high_pass<INTER>(v0, buf, t, g2, 0, wsI, wsR, wsJ, ur, ui);
    __syncthreads();  // buf handoff between passes
    high_pass<INTER>(v1, buf, t, g2, 1, wsI, wsR, wsJ, ur, ui);

    // Fused dot: overlap_ij += conj(c0'_i) * c1_j ; c1 read ONCE.
#pragma unroll
    for (int m = 0; m < 16; ++m) {
        const int y = (t & 63) | (m << 6) | ((t >> 6) << 10);
        const int idx = ((y >> 2) << 13) | (g2 << 2) | (y & 3);
        const float ar = c1r[idx], ai = c1i[idx];
        const float br = c1r[DIM_ + idx], bi = c1i[DIM_ + idx];
        acc[0] += v0[m].x * ar + v0[m].y * ai;
        acc[1] += v0[m].x * ai - v0[m].y * ar;
        acc[2] += v0[m].x * br + v0[m].y * bi;
        acc[3] += v0[m].x * bi - v0[m].y * br;
        acc[4] += v1[m].x * ar + v1[m].y * ai;
        acc[5] += v1[m].x * ai - v1[m].y * ar;
        acc[6] += v1[m].x * br + v1[m].y * bi;
        acc[7] += v1[m].x * bi - v1[m].y * br;
    }

    // wave (64) shuffle reduce -> cross-wave LDS -> one atomic per block
#pragma unroll
    for (int k = 0; k < 8; ++k)
#pragma unroll
        for (int off = 32; off > 0; off >>= 1)
            acc[k] += __shfl_down(acc[k], off, 64);
    __syncthreads();  // all waves past their buf reads before reuse as scratch
    float* red = (float*)buf;
    const int wave = t >> 6, lane = t & 63;
    if (lane == 0) {
#pragma unroll
        for (int k = 0; k < 8; ++k) red[wave * 8 + k] = acc[k];
    }
    __syncthreads();
    if (t < 8) {
        float s = 0.f;
#pragma unroll
        for (int w = 0; w < 4; ++w) s += red[w * 8 + t];
        atomicAdd(&g_acc[t], s);
    }
}

__global__ void k_zero() {
    if (threadIdx.x < 8) g_acc[threadIdx.x] = 0.f;
}

__global__ void k_fin(float* __restrict__ out) {
    if (threadIdx.x == 0) {
        float s = 0.f;
#pragma unroll
        for (int k = 0; k < 4; ++k)
            s += g_acc[2 * k] * g_acc[2 * k] + g_acc[2 * k + 1] * g_acc[2 * k + 1];
        out[0] = (float)N0_ - s;
    }
}

extern "C" void kernel_launch(void* const* d_in, const int* in_sizes, int n_in,
                              void* d_out, int out_size, void* d_ws, size_t ws_size,
                              hipStream_t stream) {
    const float* c0r = (const float*)d_in[0];
    const float* c0i = (const float*)d_in[1];
    const float* c1r = (const float*)d_in[2];
    const float* c1i = (const float*)d_in[3];
    const float* ur  = (const float*)d_in[4];
    const float* ui  = (const float*)d_in[5];
    float* out = (float*)d_out;

    const size_t need = (size_t)N0_ * DIM_ * sizeof(float2);  // 128 MB intermediate
    k_zero<<<1, 64, 0, stream>>>();
    dim3 g1(1024, N0_);
    if (d_ws != nullptr && ws_size >= need) {
        float2* wsI = (float2*)d_ws;
        k_low<true><<<g1, 512, 0, stream>>>(c0r, c0i, ur, ui, wsI, nullptr, nullptr);
        k_high<true><<<2048, 256, 0, stream>>>(wsI, nullptr, nullptr, c1r, c1i, ur, ui);
    } else {
        // fallback: identity layout, in place into code0 planes (harness restores
        // d_in from pristine copies before every timed launch)
        float* oR = (float*)c0r;
        float* oJ = (float*)c0i;
        k_low<false><<<g1, 512, 0, stream>>>(c0r, c0i, ur, ui, nullptr, oR, oJ);
        k_high<false><<<2048, 256, 0, stream>>>(nullptr, oR, oJ, c1r, c1i, ur, ui);
    }
    k_fin<<<1, 64, 0, stream>>>(out);
}

// Round 7
// 384.582 us; speedup vs baseline: 1.4093x; 1.0184x over previous
//
#include <hip/hip_runtime.h>

// QECC statevector: 23 qubits, DIM = 2^23 amplitudes, N0 = 2 vectors per code.
// Gate ind0 acts on statevector bit p = 22 - ind0:  new_d = sum_b old_b * U[b,d].
// Split: k_low does statevector bits 0..12 (gates q=22..10), k_high bits 13..22
// (gates q=9..0) + fused overlap dot. Intermediate ws is TRANSPOSED with an
// 8-element e-granule (R6-proven layout):
//   W(i, g, h, e) = i*DIM + g*8192 + h*8 + e   (h = idx>>13, l = idx&8191,
//                                               g = l>>3, e = l&7)
// k_low block (H,i) writes 64B-contiguous per 4 lanes (proven fast, R6).
// k_high block g2 = (g, eh) reads the HALF-LINE subset e = eh*4 + e', e'<4:
// 1024 strided 32B pieces = 4096 complex = 32 KB chunk -> 256-thr blocks (the
// R8 win), while sibling block g2^1 reads the other half of every 64B line.
// Siblings are adjacent block IDs -> XCD pair-swizzle puts them on the same
// XCD -> each ws line fetched once, both halves served from L2.
//
// R9: R8 showed k_high 153->125.5 us (restructure works) but k_low regressed
// ~51 us because the granule-4 layout halved its write coalescing (32B
// scatter). This round decouples: granule-8 layout for k_low writes, half-line
// strided reads for k_high. k_high internals are bit-identical to R8; only the
// global-load index changes.
//
// Empirical __launch_bounds__ cap table (2nd arg -> VGPR cap, this toolchain):
// (512,4)->64 spills, (512,2)->128 ok, (256,4)->64 spills, (256,2)->128 ok.
#define DIM_ (1 << 23)
#define N0_ 2

typedef float f32x4 __attribute__((ext_vector_type(4)));

// overlap accumulators {R00,I00,R01,I01,R10,I10,R11,I11}; zeroed each launch
__device__ float g_acc[8];

// LDS bank swizzle (bits 0,1 ^= bits 5,6 ; bits 2..4 ^= bits 7..9), bijective.
__device__ __forceinline__ int swz(int x) {
    return x ^ ((x >> 5) & 3) ^ (((x >> 7) & 7) << 2);
}

// XCD swizzle: round-robin dispatch puts linear block b on XCD b%8; map b so
// each XCD owns a CONTIGUOUS chunk range -> chunks sharing 64B lines land on
// the same XCD's L2. Bijective for grid = 8*CPX.
template <int CPX>
__device__ __forceinline__ int xcd_swz(int b) {
    return (b & 7) * CPX + (b >> 3);
}

__device__ __forceinline__ void gload(const float* __restrict__ ur,
                                      const float* __restrict__ ui, int q,
                                      float2& u00, float2& u01, float2& u10, float2& u11) {
    u00 = make_float2(ur[q * 4 + 0], ui[q * 4 + 0]);
    u01 = make_float2(ur[q * 4 + 1], ui[q * 4 + 1]);
    u10 = make_float2(ur[q * 4 + 2], ui[q * 4 + 2]);
    u11 = make_float2(ur[q * 4 + 3], ui[q * 4 + 3]);
}

// out0 = u00*a0 + u10*a1 ; out1 = u01*a0 + u11*a1   (complex, einsum convention)
__device__ __forceinline__ void bfly(float2& a0, float2& a1,
                                     float2 u00, float2 u01, float2 u10, float2 u11) {
    float2 n0, n1;
    n0.x = a0.x * u00.x - a0.y * u00.y + a1.x * u10.x - a1.y * u10.y;
    n0.y = a0.x * u00.y + a0.y * u00.x + a1.x * u10.y + a1.y * u10.x;
    n1.x = a0.x * u01.x - a0.y * u01.y + a1.x * u11.x - a1.y * u11.y;
    n1.y = a0.x * u01.y + a0.y * u01.x + a1.x * u11.y + a1.y * u11.x;
    a0 = n0; a1 = n1;
}

// Butterfly all pairs of the 16-register file v[] differing in bit log2(S), gate Q.
#define BFLY16(S, Q)                                                           \
    do {                                                                       \
        float2 u00, u01, u10, u11;                                             \
        gload(ur, ui, (Q), u00, u01, u10, u11);                                \
        _Pragma("unroll")                                                      \
        for (int m0 = 0; m0 < 16; ++m0)                                        \
            if (!(m0 & (S))) bfly(v[m0], v[m0 + (S)], u00, u01, u10, u11);     \
    } while (0)

// ---------------------------------------------------------------------------
// K1: low 13 bits. Block (H, i) owns the contiguous chunk idx = H*8192 + l.
// 512 thr x 16 complex regs. Phases (4 bits each in regs, LDS remaps between):
//   A: l bits {0,1,11,12} -> q22,q21,q11,q10      (from float4 load layout)
//   B: l bits {2..5}      -> q20..q17
//   C: l bits {6..9}      -> q16..q13
//   readout: pairs (x, x^1024) -> q12, then store transposed (granule-8, 64B
//   per 4 lanes) or identity for the in-place fallback.
// ---------------------------------------------------------------------------
template <bool INTER>
__global__ __launch_bounds__(512, 2) void k_low(
    const float* __restrict__ inr, const float* __restrict__ ini,
    const float* __restrict__ ur, const float* __restrict__ ui,
    float2* __restrict__ outI, float* __restrict__ outR, float* __restrict__ outJ) {
    __shared__ float2 buf[8192];  // 64 KB
    const int t = threadIdx.x;
    const int H = xcd_swz<128>(blockIdx.x);   // high-10-bit value this block owns
    const int base = blockIdx.y * DIM_ + (H << 13);

    float2 v[16];
    // load: reg m = (k<<2)|j  <->  l = (k<<11)|(t<<2)|j   (nt: c0 is read-once)
#pragma unroll
    for (int k = 0; k < 4; ++k) {
        const int y = (k << 11) | (t << 2);
        const f32x4 re = __builtin_nontemporal_load((const f32x4*)(inr + base + y));
        const f32x4 im = __builtin_nontemporal_load((const f32x4*)(ini + base + y));
        v[k * 4 + 0] = make_float2(re.x, im.x);
        v[k * 4 + 1] = make_float2(re.y, im.y);
        v[k * 4 + 2] = make_float2(re.z, im.z);
        v[k * 4 + 3] = make_float2(re.w, im.w);
    }
    // Phase A: m0=l0->q22, m1=l1->q21, m2=l11->q11, m3=l12->q10
    BFLY16(1, 22);
    BFLY16(2, 21);
    BFLY16(4, 11);
    BFLY16(8, 10);
#pragma unroll
    for (int m = 0; m < 16; ++m)
        buf[swz(((m >> 2) << 11) | (t << 2) | (m & 3))] = v[m];
    __syncthreads();
    // Phase B: m = l bits 2..5 ; x = (t&3) | (m<<2) | ((t>>2)<<6)
#pragma unroll
    for (int m = 0; m < 16; ++m)
        v[m] = buf[swz((t & 3) | (m << 2) | ((t >> 2) << 6))];
    BFLY16(1, 20);
    BFLY16(2, 19);
    BFLY16(4, 18);
    BFLY16(8, 17);
#pragma unroll
    for (int m = 0; m < 16; ++m)
        buf[swz((t & 3) | (m << 2) | ((t >> 2) << 6))] = v[m];  // same slots: no race
    __syncthreads();
    // Phase C: m = l bits 6..9 ; x = (t&63) | (m<<6) | ((t>>6)<<10)
#pragma unroll
    for (int m = 0; m < 16; ++m)
        v[m] = buf[swz((t & 63) | (m << 6) | ((t >> 6) << 10))];
    BFLY16(1, 16);
    BFLY16(2, 15);
    BFLY16(4, 14);
    BFLY16(8, 13);
#pragma unroll
    for (int m = 0; m < 16; ++m)
        buf[swz((t & 63) | (m << 6) | ((t >> 6) << 10))] = v[m];
    __syncthreads();
    // Readout + q12 (l bit 10 = pairs x, x^1024), stores 2 complex per float4.
    {
        float2 u00, u01, u10, u11;
        gload(ur, ui, 12, u00, u01, u10, u11);
#pragma unroll
        for (int rp = 0; rp < 4; ++rp) {
            const int x0 = (rp << 11) | (t << 1);  // even, bit10 = 0
            float2 a0 = buf[swz(x0)];
            float2 a1 = buf[swz(x0 | 1)];
            float2 b0 = buf[swz(x0 | 1024)];
            float2 b1 = buf[swz(x0 | 1025)];
            bfly(a0, b0, u00, u01, u10, u11);
            bfly(a1, b1, u00, u01, u10, u11);
            if (INTER) {
                // granule-8 transposed: o = (l>>3)*8192 + H*8 + (l&7).
                // l&7 even -> 16B aligned; 4 adjacent lanes cover 64B.
                const int l0 = x0, l1 = x0 | 1024;
                const int o0 = ((l0 >> 3) << 13) | (H << 3) | (l0 & 7);
                const int o1 = ((l1 >> 3) << 13) | (H << 3) | (l1 & 7);
                float2* p = outI + blockIdx.y * DIM_;
                *(float4*)(p + o0) = make_float4(a0.x, a0.y, a1.x, a1.y);
                *(float4*)(p + o1) = make_float4(b0.x, b0.y, b1.x, b1.y);
            } else {
                // identity layout, in-place safe (block writes only its own chunk)
                *(float2*)(outR + base + x0) = make_float2(a0.x, a1.x);
                *(float2*)(outJ + base + x0) = make_float2(a0.y, a1.y);
                *(float2*)(outR + base + (x0 | 1024)) = make_float2(b0.x, b1.x);
                *(float2*)(outJ + base + (x0 | 1024)) = make_float2(b0.y, b1.y);
            }
        }
    }
}

// ---------------------------------------------------------------------------
// One 10-bit high-pass for vector i (256 threads, 4096-elem chunk, 32 KB).
// Chunk = l-group g2 = (g, eh): l = g*8 + eh*4 + e', e'<4, spanning h=0..1023.
// Register m of thread t holds (h, e') with h = ((m>>2)<<8)|t, e' = m&3.
// Phases: A: m bits 2,3 = h bits 8,9 -> gates q1,q0
//         B: m = h bits 0..3 -> gates q9..q6
//         C: m = h bits 4..7 -> gates q5..q2
// Exit layout: y = (t&63) | (m<<6) | ((t>>6)<<10), h = y>>2, e' = y&3.
// No trailing __syncthreads.
// ---------------------------------------------------------------------------
template <bool INTER>
__device__ __forceinline__ void high_pass(
    float2 (&v)[16], float2* buf, const int t, const int g2, const int i,
    const float2* __restrict__ wsI, const float* __restrict__ wsR,
    const float* __restrict__ wsJ,
    const float* __restrict__ ur, const float* __restrict__ ui) {
    if constexpr (INTER) {
        // half-line strided reads from the granule-8 chunk of g = g2>>1:
        // f32x4 index (k<<10)|(t<<2)|(eh<<1)|jh covers complex h*8+eh*4+{0..3}.
        // Sibling block (g2^1) reads the other 32B of every 64B line; the XCD
        // pair-swizzle co-locates it -> line fetched once, L2-shared.
        const int eh = g2 & 1;
        const f32x4* wsv = (const f32x4*)(wsI + i * DIM_ + ((g2 >> 1) << 13));
#pragma unroll
        for (int k = 0; k < 4; ++k)
#pragma unroll
            for (int jh = 0; jh < 2; ++jh) {
                const f32x4 f = __builtin_nontemporal_load(
                    wsv + ((k << 10) | (t << 2) | (eh << 1) | jh));
                v[k * 4 + jh * 2 + 0] = make_float2(f.x, f.y);
                v[k * 4 + jh * 2 + 1] = make_float2(f.z, f.w);
            }
    } else {
        // identity-layout fallback: idx = h*8192 + g2*4 + e'
#pragma unroll
        for (int k = 0; k < 4; ++k) {
            const int y0 = (k << 10) | (t << 2);
            const int a = ((y0 >> 2) << 13) | (g2 << 2);
            const f32x4 re = *(const f32x4*)(wsR + i * DIM_ + a);
            const f32x4 im = *(const f32x4*)(wsJ + i * DIM_ + a);
            v[k * 4 + 0] = make_float2(re.x, im.x);
            v[k * 4 + 1] = make_float2(re.y, im.y);
            v[k * 4 + 2] = make_float2(re.z, im.z);
            v[k * 4 + 3] = make_float2(re.w, im.w);
        }
    }
    // Phase A: reg m2,m3 = h bits 8,9 -> gates q1,q0
    BFLY16(4, 1);
    BFLY16(8, 0);
#pragma unroll
    for (int m = 0; m < 16; ++m)
        buf[swz(((m >> 2) << 10) | (t << 2) | (m & 3))] = v[m];
    __syncthreads();
    // Phase B: m = h bits 0..3 = y bits 2..5 ; x = (t&3) | (m<<2) | ((t>>2)<<6)
#pragma unroll
    for (int m = 0; m < 16; ++m)
        v[m] = buf[swz((t & 3) | (m << 2) | ((t >> 2) << 6))];
    BFLY16(1, 9);
    BFLY16(2, 8);
    BFLY16(4, 7);
    BFLY16(8, 6);
#pragma unroll
    for (int m = 0; m < 16; ++m)
        buf[swz((t & 3) | (m << 2) | ((t >> 2) << 6))] = v[m];  // same slots
    __syncthreads();
    // Phase C: m = h bits 4..7 = y bits 6..9 ; x = (t&63) | (m<<6) | ((t>>6)<<10)
#pragma unroll
    for (int m = 0; m < 16; ++m)
        v[m] = buf[swz((t & 63) | (m << 6) | ((t >> 6) << 10))];
    BFLY16(1, 5);
    BFLY16(2, 4);
    BFLY16(4, 3);
    BFLY16(8, 2);
}

// ---------------------------------------------------------------------------
// K2: 256 thr, 32 KB LDS, 2048 blocks; block owns l-group g2 (l = g2*4 + e').
// Transforms i=0 into v0, i=1 into v1 (both in registers), then a SINGLE
// fused dot reading c1 once. Keeping v0+v1 live through the dot is what
// forces the allocator to throttle c1 load batching -- measured R2/R6/R8:
// VGPR 108-120, zero spill (split-dot R3-R5: 128 + ~100 MB spills; (.,4)
// launch bounds R7: capped 64 -> 476 MB spills).
// XCD swizzle: 64B lines (ws and c1) pair g2 with g2^1; swz groups 256
// consecutive g2 per XCD -> line-mates share an L2.
// ---------------------------------------------------------------------------
template <bool INTER>
__global__ __launch_bounds__(256, 2) void k_high(
    const float2* __restrict__ wsI, const float* __restrict__ wsR, const float* __restrict__ wsJ,
    const float* __restrict__ c1r, const float* __restrict__ c1i,
    const float* __restrict__ ur, const float* __restrict__ ui) {
    __shared__ float2 buf[4096];  // 32 KB; reused as reduction scratch
    const int t = threadIdx.x;
    const int g2 = xcd_swz<256>(blockIdx.x);  // l-group, 2048 blocks
    float acc[8];
#pragma unroll
    for (int k = 0; k < 8; ++k) acc[k] = 0.f;

    float2 v0[16], v1[16];
    high_pass<INTER>(v0, buf, t, g2, 0, wsI, wsR, wsJ, ur, ui);
    __syncthreads();  // buf handoff between passes
    high_pass<INTER>(v1, buf, t, g2, 1, wsI, wsR, wsJ, ur, ui);

    // Fused dot: overlap_ij += conj(c0'_i) * c1_j ; c1 read ONCE.
#pragma unroll
    for (int m = 0; m < 16; ++m) {
        const int y = (t & 63) | (m << 6) | ((t >> 6) << 10);
        const int idx = ((y >> 2) << 13) | (g2 << 2) | (y & 3);
        const float ar = c1r[idx], ai = c1i[idx];
        const float br = c1r[DIM_ + idx], bi = c1i[DIM_ + idx];
        acc[0] += v0[m].x * ar + v0[m].y * ai;
        acc[1] += v0[m].x * ai - v0[m].y * ar;
        acc[2] += v0[m].x * br + v0[m].y * bi;
        acc[3] += v0[m].x * bi - v0[m].y * br;
        acc[4] += v1[m].x * ar + v1[m].y * ai;
        acc[5] += v1[m].x * ai - v1[m].y * ar;
        acc[6] += v1[m].x * br + v1[m].y * bi;
        acc[7] += v1[m].x * bi - v1[m].y * br;
    }

    // wave (64) shuffle reduce -> cross-wave LDS -> one atomic per block
#pragma unroll
    for (int k = 0; k < 8; ++k)
#pragma unroll
        for (int off = 32; off > 0; off >>= 1)
            acc[k] += __shfl_down(acc[k], off, 64);
    __syncthreads();  // all waves past their buf reads before reuse as scratch
    float* red = (float*)buf;
    const int wave = t >> 6, lane = t & 63;
    if (lane == 0) {
#pragma unroll
        for (int k = 0; k < 8; ++k) red[wave * 8 + k] = acc[k];
    }
    __syncthreads();
    if (t < 8) {
        float s = 0.f;
#pragma unroll
        for (int w = 0; w < 4; ++w) s += red[w * 8 + t];
        atomicAdd(&g_acc[t], s);
    }
}

__global__ void k_zero() {
    if (threadIdx.x < 8) g_acc[threadIdx.x] = 0.f;
}

__global__ void k_fin(float* __restrict__ out) {
    if (threadIdx.x == 0) {
        float s = 0.f;
#pragma unroll
        for (int k = 0; k < 4; ++k)
            s += g_acc[2 * k] * g_acc[2 * k] + g_acc[2 * k + 1] * g_acc[2 * k + 1];
        out[0] = (float)N0_ - s;
    }
}

extern "C" void kernel_launch(void* const* d_in, const int* in_sizes, int n_in,
                              void* d_out, int out_size, void* d_ws, size_t ws_size,
                              hipStream_t stream) {
    const float* c0r = (const float*)d_in[0];
    const float* c0i = (const float*)d_in[1];
    const float* c1r = (const float*)d_in[2];
    const float* c1i = (const float*)d_in[3];
    const float* ur  = (const float*)d_in[4];
    const float* ui  = (const float*)d_in[5];
    float* out = (float*)d_out;

    const size_t need = (size_t)N0_ * DIM_ * sizeof(float2);  // 128 MB intermediate
    k_zero<<<1, 64, 0, stream>>>();
    dim3 g1(1024, N0_);
    if (d_ws != nullptr && ws_size >= need) {
        float2* wsI = (float2*)d_ws;
        k_low<true><<<g1, 512, 0, stream>>>(c0r, c0i, ur, ui, wsI, nullptr, nullptr);
        k_high<true><<<2048, 256, 0, stream>>>(wsI, nullptr, nullptr, c1r, c1i, ur, ui);
    } else {
        // fallback: identity layout, in place into code0 planes (harness restores
        // d_in from pristine copies before every timed launch)
        float* oR = (float*)c0r;
        float* oJ = (float*)c0i;
        k_low<false><<<g1, 512, 0, stream>>>(c0r, c0i, ur, ui, nullptr, oR, oJ);
        k_high<false><<<2048, 256, 0, stream>>>(nullptr, oR, oJ, c1r, c1i, ur, ui);
    }
    k_fin<<<1, 64, 0, stream>>>(out);
}